// Round 12
// baseline (357.609 us; speedup 1.0000x reference)
//
#include <hip/hip_runtime.h>
#include <hip/hip_bf16.h>

typedef unsigned short u16;
typedef unsigned int u32;
typedef __bf16 bf16x8 __attribute__((ext_vector_type(8)));
typedef float f32x4 __attribute__((ext_vector_type(4)));

#define DIM 128
#define NTMAX 24   // max K/32 (TXT=768)

__device__ __forceinline__ u16 f2bf_rne(float x) {
  u32 u = __float_as_uint(x);
  return (u16)((u + 0x7fffu + ((u >> 16) & 1u)) >> 16);
}
__device__ __forceinline__ float lrelu(float x) { return x > 0.f ? x : 0.01f * x; }
__device__ __forceinline__ int iclamp(int v, int hi) { return v < 0 ? 0 : (v >= hi ? hi - 1 : v); }
__device__ __forceinline__ float sane(float x) { return (x == x) ? x : 0.f; }

__device__ __forceinline__ float wred_max(float v) {
  #pragma unroll
  for (int o = 32; o > 0; o >>= 1) v = fmaxf(v, __shfl_xor(v, o, 64));
  return v;
}
__device__ __forceinline__ float wred_sum(float v) {
  #pragma unroll
  for (int o = 32; o > 0; o >>= 1) v += __shfl_xor(v, o, 64);
  return v;
}

// ---------------- CSR build ----------------
__global__ void hist_k(const int* __restrict__ dst, int* __restrict__ cnt, int E, int N) {
  int e = blockIdx.x * blockDim.x + threadIdx.x;
  if (e < E) {
    int d = dst[e];
    if (d >= 0 && d < N) atomicAdd(&cnt[d], 1);
  }
}

__global__ __launch_bounds__(1024) void scan_k(const int* __restrict__ cnt,
                                               int* __restrict__ offs, int N) {
  __shared__ int sums[1024];
  int t = threadIdx.x;
  int chunk = (N + 1023) >> 10;
  int base = t * chunk;
  int s = 0;
  for (int i = 0; i < chunk; ++i) { int idx = base + i; if (idx < N) s += cnt[idx]; }
  sums[t] = s;
  __syncthreads();
  for (int off = 1; off < 1024; off <<= 1) {
    int v = (t >= off) ? sums[t - off] : 0;
    __syncthreads();
    sums[t] += v;
    __syncthreads();
  }
  int prefix = (t > 0) ? sums[t - 1] : 0;
  for (int i = 0; i < chunk; ++i) {
    int idx = base + i;
    if (idx < N) { offs[idx] = prefix; prefix += cnt[idx]; }
  }
  if (t == 1023) offs[N] = sums[1023];
}

__global__ void scatter_k(const int* __restrict__ dst, const int* __restrict__ offs,
                          int* __restrict__ cursor, int* __restrict__ eid, int E, int N) {
  int e = blockIdx.x * blockDim.x + threadIdx.x;
  if (e < E) {
    int d = dst[e];
    if (d >= 0 && d < N) {
      int pos = offs[d] + atomicAdd(&cursor[d], 1);
      if (pos >= 0 && pos < E) eid[pos] = e;
    }
  }
}

// ================= structs =================
struct PrepArgs {
  const float* W1[3]; const float* Wmod[3]; int K[3]; int isCopy[3];
  u16* Wc[3];
};
struct PrArgs {
  const float* rel; const float* W1[3]; const float* b1[3];
  const float* bmod[3]; const float* w2[3];
  u16* PrAll; float* qr[3]; int NR;
};
struct GArgs {
  const float* A[3]; const u16* B[3]; const float* w2[3];
  u16* PdAll; u16* PsAll; float* qd[3]; float* qs[3];
  int M; int K[3];
};
struct AgArgs {
  const int* eid; const int* offs; const int* src; const int* etyp;
  const float* qd[3]; const float* qs[3]; const float* qr[3];
  const u16* PdAll; const u16* PsAll; const u16* PrAll;
  const float* alphaP; const float* gammaP;
  float* outp; int N; int NR; int E;
};

// combined bf16 B, PACKED trip-major: Wc[((k>>5)*256 + o)*32 + (k&31)]
__global__ void prep_wc_all(PrepArgs a) {
  int m = blockIdx.z;
  int K = a.K[m];
  int k = blockIdx.x * blockDim.x + threadIdx.x;
  int o = blockIdx.y;                       // 0..255
  if (k >= K) return;
  int half = (o >= 128) ? 128 : 0;
  int oo = o & 127;
  const float* W1 = a.W1[m];
  float acc;
  if (a.isCopy[m]) {
    acc = W1[oo * 384 + half + k];
  } else {
    const float* Wm = a.Wmod[m];
    acc = 0.f;
    for (int i = 0; i < 128; ++i)
      acc += W1[oo * 384 + half + i] * Wm[i * K + k];
  }
  a.Wc[m][((size_t)(k >> 5) * 256 + o) * 32 + (k & 31)] = f2bf_rne(acc);
}

// PrAll[r][m*128+o] (bf16, interleaved) + qr[m][r] (f32); grid (NR,1,3)
__global__ __launch_bounds__(128) void prep_pr_all(PrArgs a) {
  __shared__ float red[128];
  int m = blockIdx.z;
  int r = blockIdx.x;
  if (r >= a.NR) return;
  int o = threadIdx.x;
  const float* W1 = a.W1[m];
  float acc = a.b1[m][o];
  for (int i = 0; i < 128; ++i)
    acc += W1[o * 384 + 256 + i] * a.rel[r * 128 + i];
  const float* bmod = a.bmod[m];
  if (bmod != nullptr) {
    for (int i = 0; i < 128; ++i)
      acc += (W1[o * 384 + i] + W1[o * 384 + 128 + i]) * bmod[i];
  }
  a.PrAll[(size_t)r * 384 + m * 128 + o] = f2bf_rne(acc);
  red[o] = acc * a.w2[m][o];
  __syncthreads();
  for (int s = 64; s > 0; s >>= 1) {
    if (o < s) red[o] += red[o + s];
    __syncthreads();
  }
  if (o == 0) a.qr[m][r] = sane(red[0]);
}

// ---------- fused convert+GEMM (R11, unchanged) ----------
__global__ __launch_bounds__(256) void gemm_fused(GArgs g) {
  __shared__ u16 Als[NTMAX * 16 * 32];   // ≤24 KB
  __shared__ float qpart[4][16];
  int m = blockIdx.y;
  int M = g.M, K = g.K[m];
  int nt = K >> 5;                        // 4 / 16 / 24 (even)
  const u16* Bpk = g.B[m];
  const float* w2 = g.w2[m];
  int tid = threadIdx.x;
  int lane = tid & 63, wv = tid >> 6;
  int quad = lane >> 4, l16 = lane & 15;
  int row0 = blockIdx.x * 16;

  {
    int srow = tid >> 4;
    int scol = (tid & 15) * 2;
    int gr = row0 + srow;
    bool v = gr < M;
    const float* Ag = g.A[m] + (size_t)(v ? gr : 0) * K;
    for (int kb = 0; kb < nt; ++kb) {
      float2 x = make_float2(0.f, 0.f);
      if (v) x = *reinterpret_cast<const float2*>(Ag + kb * 32 + scol);
      *reinterpret_cast<u32*>(&Als[(kb * 16 + srow) * 32 + scol]) =
          (u32)f2bf_rne(x.x) | ((u32)f2bf_rne(x.y) << 16);
    }
  }
  __syncthreads();

  const u16* Bpg = Bpk + (size_t)(wv * 64 + l16) * 32 + quad * 8;

  f32x4 acc[4];
  #pragma unroll
  for (int t = 0; t < 4; ++t) acc[t] = (f32x4){0.f, 0.f, 0.f, 0.f};

  for (int kb = 0; kb < nt; kb += 2) {
    bf16x8 a0 = *reinterpret_cast<const bf16x8*>(&Als[(kb * 16 + l16) * 32 + quad * 8]);
    bf16x8 a1 = *reinterpret_cast<const bf16x8*>(&Als[((kb + 1) * 16 + l16) * 32 + quad * 8]);
    const u16* b0p = Bpg + (size_t)kb * 8192;
    bf16x8 b00 = *reinterpret_cast<const bf16x8*>(b0p);
    bf16x8 b01 = *reinterpret_cast<const bf16x8*>(b0p + 512);
    bf16x8 b02 = *reinterpret_cast<const bf16x8*>(b0p + 1024);
    bf16x8 b03 = *reinterpret_cast<const bf16x8*>(b0p + 1536);
    const u16* b1p = b0p + 8192;
    bf16x8 b10 = *reinterpret_cast<const bf16x8*>(b1p);
    bf16x8 b11 = *reinterpret_cast<const bf16x8*>(b1p + 512);
    bf16x8 b12 = *reinterpret_cast<const bf16x8*>(b1p + 1024);
    bf16x8 b13 = *reinterpret_cast<const bf16x8*>(b1p + 1536);

    acc[0] = __builtin_amdgcn_mfma_f32_16x16x32_bf16(a0, b00, acc[0], 0, 0, 0);
    acc[1] = __builtin_amdgcn_mfma_f32_16x16x32_bf16(a0, b01, acc[1], 0, 0, 0);
    acc[2] = __builtin_amdgcn_mfma_f32_16x16x32_bf16(a0, b02, acc[2], 0, 0, 0);
    acc[3] = __builtin_amdgcn_mfma_f32_16x16x32_bf16(a0, b03, acc[3], 0, 0, 0);
    acc[0] = __builtin_amdgcn_mfma_f32_16x16x32_bf16(a1, b10, acc[0], 0, 0, 0);
    acc[1] = __builtin_amdgcn_mfma_f32_16x16x32_bf16(a1, b11, acc[1], 0, 0, 0);
    acc[2] = __builtin_amdgcn_mfma_f32_16x16x32_bf16(a1, b12, acc[2], 0, 0, 0);
    acc[3] = __builtin_amdgcn_mfma_f32_16x16x32_bf16(a1, b13, acc[3], 0, 0, 0);
  }

  u16* PdAll = g.PdAll;
  u16* PsAll = g.PsAll;
  float w2c[4];
  #pragma unroll
  for (int t = 0; t < 4; ++t) w2c[t] = w2[(wv & 1) * 64 + t * 16 + l16];

  float part[4];
  #pragma unroll
  for (int r = 0; r < 4; ++r) {
    int rr = row0 + quad * 4 + r;
    bool ok = rr < M;
    float qp = 0.f;
    #pragma unroll
    for (int t = 0; t < 4; ++t) {
      int c = (wv & 1) * 64 + t * 16 + l16;
      if (ok) {
        if (wv < 2) PdAll[(size_t)rr * 384 + m * 128 + c] = f2bf_rne(acc[t][r]);
        else        PsAll[(size_t)rr * 384 + m * 128 + c] = f2bf_rne(acc[t][r]);
      }
      qp += acc[t][r] * w2c[t];
    }
    #pragma unroll
    for (int mk = 1; mk < 16; mk <<= 1) qp += __shfl_xor(qp, mk, 64);
    part[r] = qp;
  }
  if (l16 == 0) {
    #pragma unroll
    for (int r = 0; r < 4; ++r) qpart[wv][quad * 4 + r] = part[r];
  }
  __syncthreads();
  if (tid < 32) {
    int row = tid & 15;
    int rr = row0 + row;
    if (rr < M) {
      if (tid < 16) g.qd[m][rr] = sane(qpart[0][row] + qpart[1][row]);
      else          g.qs[m][rr] = sane(qpart[2][row] + qpart[3][row]);
    }
  }
}

// ---------- modality-split softmax+aggregate: 1 block = 1 node, 3 waves ----------
// wave m handles modality m end-to-end; combine via LDS at the end.
__global__ __launch_bounds__(192) void aggregate_split(AgArgs a) {
  __shared__ float hb[3][128];
  int n = blockIdx.x;
  if (n >= a.N) return;
  int tid = threadIdx.x;
  int m = tid / 64;              // modality for this wave
  int lane = tid & 63;
  int N = a.N, NR = a.NR, E = a.E;
  int eb = a.offs[n], ee = a.offs[n + 1];
  if (eb < 0) eb = 0;
  if (eb > E) eb = E;
  if (ee < eb) ee = eb;
  if (ee > E) ee = E;
  int En = ee - eb;

  float al = a.alphaP[0];
  if (!(al > 0.f && al < 1.f)) al = 0.1f;
  float ga = a.gammaP[0];
  if (!(ga > 0.f && ga < 1.f)) ga = 0.8f;
  float coefm = (m == 0) ? (1.f - al - ga) : (m == 1 ? al : ga);

  const float* qs = a.qs[m];
  const float* qr = a.qr[m];
  float qdn = sane(a.qd[m][n]);

  // pass 1: segment max (this modality only)
  float mx = -1e30f;
  for (int i = lane; i < En; i += 64) {
    int e = iclamp(a.eid[eb + i], E);
    int s = iclamp(a.src[e], N);
    int t = iclamp(a.etyp[e], NR);
    mx = fmaxf(mx, lrelu(qdn + qs[s] + qr[t]));
  }
  mx = wred_max(mx);

  int dlo = 2 * lane;
  const u16* PsM = a.PsAll + m * 128 + dlo;
  const u16* PrM = a.PrAll + m * 128 + dlo;

  // pass 2: z + unnormalized accumulation
  float z = 0.f, a0 = 0.f, a1 = 0.f;
  for (int c0 = 0; c0 < En; c0 += 64) {
    int cn = min(64, En - c0);
    float wraw = 0.f;
    int s = 0, t = 0;
    if (lane < cn) {
      int e = iclamp(a.eid[eb + c0 + lane], E);
      s = iclamp(a.src[e], N);
      t = iclamp(a.etyp[e], NR);
      float b = lrelu(qdn + qs[s] + qr[t]);
      wraw = __expf(fmaxf(fminf(b - mx, 0.f), -80.f));
    }
    z += wraw;
    for (int j = 0; j < cn; ++j) {
      float wj = __shfl(wraw, j, 64);
      int sj = __shfl(s, j, 64);
      int tj = __shfl(t, j, 64);
      u32 pu = *reinterpret_cast<const u32*>(PsM + (size_t)sj * 384);
      u32 ru = *reinterpret_cast<const u32*>(PrM + (size_t)tj * 384);
      float p0 = __uint_as_float(pu << 16), p1 = __uint_as_float(pu & 0xffff0000u);
      float r0 = __uint_as_float(ru << 16), r1 = __uint_as_float(ru & 0xffff0000u);
      a0 = fmaf(wj, p0 + r0, a0);
      a1 = fmaf(wj, p1 + r1, a1);
    }
  }
  z = wred_sum(z);

  float h0 = 0.f, h1 = 0.f;
  if (En > 0 && z > 0.f) {
    float rz = 1.f / z;
    u32 du = *reinterpret_cast<const u32*>(a.PdAll + (size_t)n * 384 + m * 128 + dlo);
    float d0 = __uint_as_float(du << 16), d1 = __uint_as_float(du & 0xffff0000u);
    h0 = lrelu(d0 + a0 * rz);
    h1 = lrelu(d1 + a1 * rz);
  }
  hb[m][dlo]     = coefm * h0;
  hb[m][dlo + 1] = coefm * h1;
  __syncthreads();
  if (m == 0) {
    float o0 = hb[0][dlo] + hb[1][dlo] + hb[2][dlo];
    float o1 = hb[0][dlo + 1] + hb[1][dlo + 1] + hb[2][dlo + 1];
    float2 st = make_float2(sane(o0), sane(o1));
    *reinterpret_cast<float2*>(a.outp + (size_t)n * 128 + dlo) = st;
  }
}

extern "C" void kernel_launch(void* const* d_in, const int* in_sizes, int n_in,
                              void* d_out, int out_size, void* d_ws, size_t ws_size,
                              hipStream_t stream) {
  const int* ei        = (const int*)d_in[1];
  const int* et        = (const int*)d_in[2];
  const float* visual  = (const float*)d_in[3];
  const float* textual = (const float*)d_in[4];
  const float* semb    = (const float*)d_in[5];
  const float* relemb  = (const float*)d_in[6];
  const float* W1s = (const float*)d_in[7];
  const float* b1s = (const float*)d_in[8];
  const float* w2s = (const float*)d_in[9];
  const float* W1v = (const float*)d_in[10];
  const float* b1v = (const float*)d_in[11];
  const float* w2v = (const float*)d_in[12];
  const float* W1t = (const float*)d_in[13];
  const float* b1t = (const float*)d_in[14];
  const float* w2t = (const float*)d_in[15];
  const float* Wv  = (const float*)d_in[16];
  const float* bv  = (const float*)d_in[17];
  const float* Wt  = (const float*)d_in[18];
  const float* bt  = (const float*)d_in[19];
  const float* alphaP = (const float*)d_in[20];
  const float* gammaP = (const float*)d_in[21];
  float* outp = (float*)d_out;

  const int E   = in_sizes[2];
  const int N   = in_sizes[5] / DIM;
  const int NR  = in_sizes[6] / DIM;
  const int VIS = in_sizes[3] / N;   // 512
  const int TXT = in_sizes[4] / N;   // 768
  const int KMAX = (TXT > VIS) ? TXT : VIS;
  int Ks[3] = {DIM, VIS, TXT};
  const int NT16 = (N + 15) / 16;

  const float* W1a[3]   = {W1s, W1v, W1t};
  const float* b1a[3]   = {b1s, b1v, b1t};
  const float* w2a[3]   = {w2s, w2v, w2t};
  const float* Wmoda[3] = {nullptr, Wv, Wt};
  const float* bmoda[3] = {nullptr, bv, bt};
  const float* Amoda[3] = {semb, visual, textual};

  const int* esrc = ei;
  const int* edst = ei + E;
  int egrid = (E + 255) / 256;

  size_t off = 0;
  auto take = [&](size_t bytes) -> size_t {
    size_t o = off;
    off = (off + bytes + 255) & ~(size_t)255;
    return o;
  };
  size_t o_cnt  = take((size_t)2 * N * 4);
  size_t o_offs = take((size_t)(N + 1) * 4);
  size_t o_eid  = take((size_t)E * 4);
  size_t meta_end = off;                       // [0, meta_end) zeroed in one memset
  size_t o_qdm[3], o_qsm[3], o_qrm[3], o_Wcm[3];
  for (int m = 0; m < 3; ++m) {
    o_qdm[m] = take((size_t)N * 4);
    o_qsm[m] = take((size_t)N * 4);
    o_qrm[m] = take((size_t)NR * 4);
    o_Wcm[m] = take((size_t)256 * Ks[m] * 2);
  }
  size_t o_PrAll = take((size_t)NR * 384 * 2);
  size_t o_PdAll = take((size_t)N * 384 * 2);
  size_t o_PsAll = take((size_t)N * 384 * 2);
  size_t need = off;                           // ~17.5 MB (ws proven ≥ 47 MB)

  if (ws_size < need) {
    hipMemsetAsync(d_out, 0, (size_t)out_size * 4, stream);  // finite diagnostic
    return;
  }

  char* w = (char*)d_ws;
  int* counts = (int*)(w + o_cnt);
  int* cursor = counts + N;
  int* offs   = (int*)(w + o_offs);
  int* eid    = (int*)(w + o_eid);

  hipMemsetAsync(w, 0, meta_end, stream);   // counts+cursor+offs+eid in one shot
  hist_k<<<egrid, 256, 0, stream>>>(edst, counts, E, N);
  scan_k<<<1, 1024, 0, stream>>>(counts, offs, N);
  scatter_k<<<egrid, 256, 0, stream>>>(edst, offs, cursor, eid, E, N);

  PrepArgs pa;
  PrArgs ra;
  GArgs ga;
  AgArgs aa;
  ra.rel = relemb; ra.NR = NR;
  ra.PrAll = (u16*)(w + o_PrAll);
  ga.M = N;
  ga.PdAll = (u16*)(w + o_PdAll);
  ga.PsAll = (u16*)(w + o_PsAll);
  for (int m = 0; m < 3; ++m) {
    pa.W1[m] = W1a[m]; pa.Wmod[m] = Wmoda[m]; pa.K[m] = Ks[m];
    pa.isCopy[m] = (m == 0);
    pa.Wc[m] = (u16*)(w + o_Wcm[m]);
    ra.W1[m] = W1a[m]; ra.b1[m] = b1a[m]; ra.bmod[m] = bmoda[m]; ra.w2[m] = w2a[m];
    ra.qr[m] = (float*)(w + o_qrm[m]);
    ga.A[m] = Amoda[m]; ga.B[m] = (const u16*)(w + o_Wcm[m]); ga.w2[m] = w2a[m];
    ga.qd[m] = (float*)(w + o_qdm[m]); ga.qs[m] = (float*)(w + o_qsm[m]);
    ga.K[m] = Ks[m];
    aa.qd[m] = (const float*)(w + o_qdm[m]);
    aa.qs[m] = (const float*)(w + o_qsm[m]);
    aa.qr[m] = (const float*)(w + o_qrm[m]);
  }
  aa.PdAll = (const u16*)(w + o_PdAll);
  aa.PsAll = (const u16*)(w + o_PsAll);
  aa.PrAll = (const u16*)(w + o_PrAll);
  aa.eid = eid; aa.offs = offs; aa.src = esrc; aa.etyp = et;
  aa.alphaP = alphaP; aa.gammaP = gammaP;
  aa.outp = outp; aa.N = N; aa.NR = NR; aa.E = E;

  prep_wc_all<<<dim3((KMAX + 255) / 256, 256, 3), 256, 0, stream>>>(pa);
  prep_pr_all<<<dim3(NR, 1, 3), 128, 0, stream>>>(ra);
  gemm_fused<<<dim3(NT16, 3), 256, 0, stream>>>(ga);
  aggregate_split<<<N, 192, 0, stream>>>(aa);
}

// Round 13
// 297.748 us; speedup vs baseline: 1.2010x; 1.2010x over previous
//
#include <hip/hip_runtime.h>
#include <hip/hip_bf16.h>

typedef unsigned short u16;
typedef unsigned int u32;
typedef __bf16 bf16x8 __attribute__((ext_vector_type(8)));
typedef float f32x4 __attribute__((ext_vector_type(4)));

#define DIM 128
#define NTMAX 24   // max K/32 (TXT=768)

__device__ __forceinline__ u16 f2bf_rne(float x) {
  u32 u = __float_as_uint(x);
  return (u16)((u + 0x7fffu + ((u >> 16) & 1u)) >> 16);
}
__device__ __forceinline__ float lrelu(float x) { return x > 0.f ? x : 0.01f * x; }
__device__ __forceinline__ int iclamp(int v, int hi) { return v < 0 ? 0 : (v >= hi ? hi - 1 : v); }
__device__ __forceinline__ float sane(float x) { return (x == x) ? x : 0.f; }

__device__ __forceinline__ float wred_max(float v) {
  #pragma unroll
  for (int o = 32; o > 0; o >>= 1) v = fmaxf(v, __shfl_xor(v, o, 64));
  return v;
}
__device__ __forceinline__ float wred_sum(float v) {
  #pragma unroll
  for (int o = 32; o > 0; o >>= 1) v += __shfl_xor(v, o, 64);
  return v;
}

// ---------------- CSR build ----------------
__global__ void hist_k(const int* __restrict__ dst, int* __restrict__ cnt, int E, int N) {
  int e = blockIdx.x * blockDim.x + threadIdx.x;
  if (e < E) {
    int d = dst[e];
    if (d >= 0 && d < N) atomicAdd(&cnt[d], 1);
  }
}

__global__ __launch_bounds__(1024) void scan_k(const int* __restrict__ cnt,
                                               int* __restrict__ offs, int N) {
  __shared__ int sums[1024];
  int t = threadIdx.x;
  int chunk = (N + 1023) >> 10;
  int base = t * chunk;
  int s = 0;
  for (int i = 0; i < chunk; ++i) { int idx = base + i; if (idx < N) s += cnt[idx]; }
  sums[t] = s;
  __syncthreads();
  for (int off = 1; off < 1024; off <<= 1) {
    int v = (t >= off) ? sums[t - off] : 0;
    __syncthreads();
    sums[t] += v;
    __syncthreads();
  }
  int prefix = (t > 0) ? sums[t - 1] : 0;
  for (int i = 0; i < chunk; ++i) {
    int idx = base + i;
    if (idx < N) { offs[idx] = prefix; prefix += cnt[idx]; }
  }
  if (t == 1023) offs[N] = sums[1023];
}

__global__ void scatter_k(const int* __restrict__ dst, const int* __restrict__ offs,
                          int* __restrict__ cursor, int* __restrict__ eid, int E, int N) {
  int e = blockIdx.x * blockDim.x + threadIdx.x;
  if (e < E) {
    int d = dst[e];
    if (d >= 0 && d < N) {
      int pos = offs[d] + atomicAdd(&cursor[d], 1);
      if (pos >= 0 && pos < E) eid[pos] = e;
    }
  }
}

// ================= structs =================
struct PrepArgs {
  const float* W1[3]; const float* Wmod[3]; int K[3]; int isCopy[3];
  u16* Wc[3];
};
struct PrArgs {
  const float* rel; const float* W1[3]; const float* b1[3];
  const float* bmod[3]; const float* w2[3];
  u16* PrAll; float* qr[3]; int NR;
};
struct GArgs {
  const float* A[3]; const u16* B[3]; const float* w2[3];
  u16* PdAll; u16* PsAll; float* qd[3]; float* qs[3];
  int M; int K[3];
};
struct AgArgs {
  const int* eid; const int* offs; const int* src; const int* etyp;
  const float* qd[3]; const float* qs[3]; const float* qr[3];
  const u16* PdAll; const u16* PsAll; const u16* PrAll;
  const float* alphaP; const float* gammaP;
  float* outp; int N; int NR; int E;
};

// combined bf16 B, PACKED trip-major: Wc[((k>>5)*256 + o)*32 + (k&31)]
__global__ void prep_wc_all(PrepArgs a) {
  int m = blockIdx.z;
  int K = a.K[m];
  int k = blockIdx.x * blockDim.x + threadIdx.x;
  int o = blockIdx.y;                       // 0..255
  if (k >= K) return;
  int half = (o >= 128) ? 128 : 0;
  int oo = o & 127;
  const float* W1 = a.W1[m];
  float acc;
  if (a.isCopy[m]) {
    acc = W1[oo * 384 + half + k];
  } else {
    const float* Wm = a.Wmod[m];
    acc = 0.f;
    for (int i = 0; i < 128; ++i)
      acc += W1[oo * 384 + half + i] * Wm[i * K + k];
  }
  a.Wc[m][((size_t)(k >> 5) * 256 + o) * 32 + (k & 31)] = f2bf_rne(acc);
}

// PrAll[r][m*128+o] (bf16, interleaved) + qr[m][r] (f32); grid (NR,1,3)
__global__ __launch_bounds__(128) void prep_pr_all(PrArgs a) {
  __shared__ float red[128];
  int m = blockIdx.z;
  int r = blockIdx.x;
  if (r >= a.NR) return;
  int o = threadIdx.x;
  const float* W1 = a.W1[m];
  float acc = a.b1[m][o];
  for (int i = 0; i < 128; ++i)
    acc += W1[o * 384 + 256 + i] * a.rel[r * 128 + i];
  const float* bmod = a.bmod[m];
  if (bmod != nullptr) {
    for (int i = 0; i < 128; ++i)
      acc += (W1[o * 384 + i] + W1[o * 384 + 128 + i]) * bmod[i];
  }
  a.PrAll[(size_t)r * 384 + m * 128 + o] = f2bf_rne(acc);
  red[o] = acc * a.w2[m][o];
  __syncthreads();
  for (int s = 64; s > 0; s >>= 1) {
    if (o < s) red[o] += red[o + s];
    __syncthreads();
  }
  if (o == 0) a.qr[m][r] = sane(red[0]);
}

// ---------- fused convert+GEMM (R11, unchanged) ----------
__global__ __launch_bounds__(256) void gemm_fused(GArgs g) {
  __shared__ u16 Als[NTMAX * 16 * 32];   // ≤24 KB
  __shared__ float qpart[4][16];
  int m = blockIdx.y;
  int M = g.M, K = g.K[m];
  int nt = K >> 5;                        // 4 / 16 / 24 (even)
  const u16* Bpk = g.B[m];
  const float* w2 = g.w2[m];
  int tid = threadIdx.x;
  int lane = tid & 63, wv = tid >> 6;
  int quad = lane >> 4, l16 = lane & 15;
  int row0 = blockIdx.x * 16;

  {
    int srow = tid >> 4;
    int scol = (tid & 15) * 2;
    int gr = row0 + srow;
    bool v = gr < M;
    const float* Ag = g.A[m] + (size_t)(v ? gr : 0) * K;
    for (int kb = 0; kb < nt; ++kb) {
      float2 x = make_float2(0.f, 0.f);
      if (v) x = *reinterpret_cast<const float2*>(Ag + kb * 32 + scol);
      *reinterpret_cast<u32*>(&Als[(kb * 16 + srow) * 32 + scol]) =
          (u32)f2bf_rne(x.x) | ((u32)f2bf_rne(x.y) << 16);
    }
  }
  __syncthreads();

  const u16* Bpg = Bpk + (size_t)(wv * 64 + l16) * 32 + quad * 8;

  f32x4 acc[4];
  #pragma unroll
  for (int t = 0; t < 4; ++t) acc[t] = (f32x4){0.f, 0.f, 0.f, 0.f};

  for (int kb = 0; kb < nt; kb += 2) {
    bf16x8 a0 = *reinterpret_cast<const bf16x8*>(&Als[(kb * 16 + l16) * 32 + quad * 8]);
    bf16x8 a1 = *reinterpret_cast<const bf16x8*>(&Als[((kb + 1) * 16 + l16) * 32 + quad * 8]);
    const u16* b0p = Bpg + (size_t)kb * 8192;
    bf16x8 b00 = *reinterpret_cast<const bf16x8*>(b0p);
    bf16x8 b01 = *reinterpret_cast<const bf16x8*>(b0p + 512);
    bf16x8 b02 = *reinterpret_cast<const bf16x8*>(b0p + 1024);
    bf16x8 b03 = *reinterpret_cast<const bf16x8*>(b0p + 1536);
    const u16* b1p = b0p + 8192;
    bf16x8 b10 = *reinterpret_cast<const bf16x8*>(b1p);
    bf16x8 b11 = *reinterpret_cast<const bf16x8*>(b1p + 512);
    bf16x8 b12 = *reinterpret_cast<const bf16x8*>(b1p + 1024);
    bf16x8 b13 = *reinterpret_cast<const bf16x8*>(b1p + 1536);

    acc[0] = __builtin_amdgcn_mfma_f32_16x16x32_bf16(a0, b00, acc[0], 0, 0, 0);
    acc[1] = __builtin_amdgcn_mfma_f32_16x16x32_bf16(a0, b01, acc[1], 0, 0, 0);
    acc[2] = __builtin_amdgcn_mfma_f32_16x16x32_bf16(a0, b02, acc[2], 0, 0, 0);
    acc[3] = __builtin_amdgcn_mfma_f32_16x16x32_bf16(a0, b03, acc[3], 0, 0, 0);
    acc[0] = __builtin_amdgcn_mfma_f32_16x16x32_bf16(a1, b10, acc[0], 0, 0, 0);
    acc[1] = __builtin_amdgcn_mfma_f32_16x16x32_bf16(a1, b11, acc[1], 0, 0, 0);
    acc[2] = __builtin_amdgcn_mfma_f32_16x16x32_bf16(a1, b12, acc[2], 0, 0, 0);
    acc[3] = __builtin_amdgcn_mfma_f32_16x16x32_bf16(a1, b13, acc[3], 0, 0, 0);
  }

  u16* PdAll = g.PdAll;
  u16* PsAll = g.PsAll;
  float w2c[4];
  #pragma unroll
  for (int t = 0; t < 4; ++t) w2c[t] = w2[(wv & 1) * 64 + t * 16 + l16];

  float part[4];
  #pragma unroll
  for (int r = 0; r < 4; ++r) {
    int rr = row0 + quad * 4 + r;
    bool ok = rr < M;
    float qp = 0.f;
    #pragma unroll
    for (int t = 0; t < 4; ++t) {
      int c = (wv & 1) * 64 + t * 16 + l16;
      if (ok) {
        if (wv < 2) PdAll[(size_t)rr * 384 + m * 128 + c] = f2bf_rne(acc[t][r]);
        else        PsAll[(size_t)rr * 384 + m * 128 + c] = f2bf_rne(acc[t][r]);
      }
      qp += acc[t][r] * w2c[t];
    }
    #pragma unroll
    for (int mk = 1; mk < 16; mk <<= 1) qp += __shfl_xor(qp, mk, 64);
    part[r] = qp;
  }
  if (l16 == 0) {
    #pragma unroll
    for (int r = 0; r < 4; ++r) qpart[wv][quad * 4 + r] = part[r];
  }
  __syncthreads();
  if (tid < 32) {
    int row = tid & 15;
    int rr = row0 + row;
    if (rr < M) {
      if (tid < 16) g.qd[m][rr] = sane(qpart[0][row] + qpart[1][row]);
      else          g.qs[m][rr] = sane(qpart[2][row] + qpart[3][row]);
    }
  }
}

// fused 3-modality softmax+aggregate (R11 structure) with 4×-unrolled j-loop
__global__ __launch_bounds__(256) void aggregate_all(AgArgs a) {
  int n = blockIdx.x * 4 + (threadIdx.x >> 6);
  if (n >= a.N) return;
  int lane = threadIdx.x & 63;
  int N = a.N, NR = a.NR, E = a.E;
  int eb = a.offs[n], ee = a.offs[n + 1];
  if (eb < 0) eb = 0;
  if (eb > E) eb = E;
  if (ee < eb) ee = eb;
  if (ee > E) ee = E;
  int En = ee - eb;

  float al = a.alphaP[0];
  if (!(al > 0.f && al < 1.f)) al = 0.1f;
  float ga = a.gammaP[0];
  if (!(ga > 0.f && ga < 1.f)) ga = 0.8f;
  float coef[3] = {1.f - al - ga, al, ga};

  float qdn[3];
  #pragma unroll
  for (int m = 0; m < 3; ++m) qdn[m] = sane(a.qd[m][n]);

  // pass 1: segment max per modality
  float mx[3] = {-1e30f, -1e30f, -1e30f};
  for (int i = lane; i < En; i += 64) {
    int e = iclamp(a.eid[eb + i], E);
    int s = iclamp(a.src[e], N);
    int t = iclamp(a.etyp[e], NR);
    #pragma unroll
    for (int m = 0; m < 3; ++m)
      mx[m] = fmaxf(mx[m], lrelu(qdn[m] + a.qs[m][s] + a.qr[m][t]));
  }
  #pragma unroll
  for (int m = 0; m < 3; ++m) mx[m] = wred_max(mx[m]);

  const u16* PsAll = a.PsAll;
  const u16* PrAll = a.PrAll;
  int dlo = 2 * lane;

  // pass 2: z + unnormalized accumulation; j-loop unrolled ×4 for MLP
  float z[3] = {0.f, 0.f, 0.f};
  float a0[3] = {0.f, 0.f, 0.f};
  float a1[3] = {0.f, 0.f, 0.f};
  for (int c0 = 0; c0 < En; c0 += 64) {
    int cn = min(64, En - c0);
    float wr[3] = {0.f, 0.f, 0.f};
    int s = 0, t = 0;
    if (lane < cn) {
      int e = iclamp(a.eid[eb + c0 + lane], E);
      s = iclamp(a.src[e], N);
      t = iclamp(a.etyp[e], NR);
      #pragma unroll
      for (int m = 0; m < 3; ++m) {
        float b = lrelu(qdn[m] + a.qs[m][s] + a.qr[m][t]);
        float arg = fmaxf(fminf(b - mx[m], 0.f), -80.f);
        wr[m] = __expf(arg);
      }
    }
    #pragma unroll
    for (int m = 0; m < 3; ++m) z[m] += wr[m];

    int cnR = (cn + 3) & ~3;   // tail lanes have wr=0, s=t=0 → harmless
    for (int j = 0; j < cnR; j += 4) {
      int sj[4], tj[4];
      float wj[4][3];
      #pragma unroll
      for (int u = 0; u < 4; ++u) {
        sj[u] = __shfl(s, j + u, 64);
        tj[u] = __shfl(t, j + u, 64);
        wj[u][0] = __shfl(wr[0], j + u, 64);
        wj[u][1] = __shfl(wr[1], j + u, 64);
        wj[u][2] = __shfl(wr[2], j + u, 64);
      }
      u32 pu[4][3], ru[4][3];
      #pragma unroll
      for (int u = 0; u < 4; ++u) {
        const u16* ps = PsAll + (size_t)sj[u] * 384 + dlo;
        const u16* pr = PrAll + (size_t)tj[u] * 384 + dlo;
        #pragma unroll
        for (int m = 0; m < 3; ++m) {
          pu[u][m] = *reinterpret_cast<const u32*>(ps + m * 128);
          ru[u][m] = *reinterpret_cast<const u32*>(pr + m * 128);
        }
      }
      #pragma unroll
      for (int u = 0; u < 4; ++u) {
        #pragma unroll
        for (int m = 0; m < 3; ++m) {
          float ps0 = __uint_as_float(pu[u][m] << 16);
          float ps1 = __uint_as_float(pu[u][m] & 0xffff0000u);
          float pr0 = __uint_as_float(ru[u][m] << 16);
          float pr1 = __uint_as_float(ru[u][m] & 0xffff0000u);
          a0[m] = fmaf(wj[u][m], ps0 + pr0, a0[m]);
          a1[m] = fmaf(wj[u][m], ps1 + pr1, a1[m]);
        }
      }
    }
  }
  #pragma unroll
  for (int m = 0; m < 3; ++m) z[m] = wred_sum(z[m]);

  float o0 = 0.f, o1 = 0.f;
  const u16* pd = a.PdAll + (size_t)n * 384 + dlo;
  #pragma unroll
  for (int m = 0; m < 3; ++m) {
    float h0 = 0.f, h1 = 0.f;
    if (En > 0 && z[m] > 0.f) {
      float rz = 1.f / z[m];
      u32 du = *reinterpret_cast<const u32*>(pd + m * 128);
      float pd0 = __uint_as_float(du << 16), pd1 = __uint_as_float(du & 0xffff0000u);
      h0 = lrelu(pd0 + a0[m] * rz);
      h1 = lrelu(pd1 + a1[m] * rz);
    }
    o0 = fmaf(coef[m], h0, o0);
    o1 = fmaf(coef[m], h1, o1);
  }
  float* op = a.outp + (size_t)n * 128 + dlo;
  op[0] = sane(o0);
  op[1] = sane(o1);
}

extern "C" void kernel_launch(void* const* d_in, const int* in_sizes, int n_in,
                              void* d_out, int out_size, void* d_ws, size_t ws_size,
                              hipStream_t stream) {
  const int* ei        = (const int*)d_in[1];
  const int* et        = (const int*)d_in[2];
  const float* visual  = (const float*)d_in[3];
  const float* textual = (const float*)d_in[4];
  const float* semb    = (const float*)d_in[5];
  const float* relemb  = (const float*)d_in[6];
  const float* W1s = (const float*)d_in[7];
  const float* b1s = (const float*)d_in[8];
  const float* w2s = (const float*)d_in[9];
  const float* W1v = (const float*)d_in[10];
  const float* b1v = (const float*)d_in[11];
  const float* w2v = (const float*)d_in[12];
  const float* W1t = (const float*)d_in[13];
  const float* b1t = (const float*)d_in[14];
  const float* w2t = (const float*)d_in[15];
  const float* Wv  = (const float*)d_in[16];
  const float* bv  = (const float*)d_in[17];
  const float* Wt  = (const float*)d_in[18];
  const float* bt  = (const float*)d_in[19];
  const float* alphaP = (const float*)d_in[20];
  const float* gammaP = (const float*)d_in[21];
  float* outp = (float*)d_out;

  const int E   = in_sizes[2];
  const int N   = in_sizes[5] / DIM;
  const int NR  = in_sizes[6] / DIM;
  const int VIS = in_sizes[3] / N;   // 512
  const int TXT = in_sizes[4] / N;   // 768
  const int KMAX = (TXT > VIS) ? TXT : VIS;
  int Ks[3] = {DIM, VIS, TXT};
  const int NT16 = (N + 15) / 16;

  const float* W1a[3]   = {W1s, W1v, W1t};
  const float* b1a[3]   = {b1s, b1v, b1t};
  const float* w2a[3]   = {w2s, w2v, w2t};
  const float* Wmoda[3] = {nullptr, Wv, Wt};
  const float* bmoda[3] = {nullptr, bv, bt};
  const float* Amoda[3] = {semb, visual, textual};

  const int* esrc = ei;
  const int* edst = ei + E;
  int egrid = (E + 255) / 256;

  size_t off = 0;
  auto take = [&](size_t bytes) -> size_t {
    size_t o = off;
    off = (off + bytes + 255) & ~(size_t)255;
    return o;
  };
  size_t o_cnt  = take((size_t)2 * N * 4);
  size_t o_offs = take((size_t)(N + 1) * 4);
  size_t o_eid  = take((size_t)E * 4);
  size_t meta_end = off;
  size_t o_qdm[3], o_qsm[3], o_qrm[3], o_Wcm[3];
  for (int m = 0; m < 3; ++m) {
    o_qdm[m] = take((size_t)N * 4);
    o_qsm[m] = take((size_t)N * 4);
    o_qrm[m] = take((size_t)NR * 4);
    o_Wcm[m] = take((size_t)256 * Ks[m] * 2);
  }
  size_t o_PrAll = take((size_t)NR * 384 * 2);
  size_t o_PdAll = take((size_t)N * 384 * 2);
  size_t o_PsAll = take((size_t)N * 384 * 2);
  size_t need = off;                           // ~17.5 MB

  if (ws_size < need) {
    hipMemsetAsync(d_out, 0, (size_t)out_size * 4, stream);  // finite diagnostic
    return;
  }

  char* w = (char*)d_ws;
  int* counts = (int*)(w + o_cnt);
  int* cursor = counts + N;
  int* offs   = (int*)(w + o_offs);
  int* eid    = (int*)(w + o_eid);

  hipMemsetAsync(w, 0, meta_end, stream);
  hist_k<<<egrid, 256, 0, stream>>>(edst, counts, E, N);
  scan_k<<<1, 1024, 0, stream>>>(counts, offs, N);
  scatter_k<<<egrid, 256, 0, stream>>>(edst, offs, cursor, eid, E, N);

  PrepArgs pa;
  PrArgs ra;
  GArgs ga;
  AgArgs aa;
  ra.rel = relemb; ra.NR = NR;
  ra.PrAll = (u16*)(w + o_PrAll);
  ga.M = N;
  ga.PdAll = (u16*)(w + o_PdAll);
  ga.PsAll = (u16*)(w + o_PsAll);
  for (int m = 0; m < 3; ++m) {
    pa.W1[m] = W1a[m]; pa.Wmod[m] = Wmoda[m]; pa.K[m] = Ks[m];
    pa.isCopy[m] = (m == 0);
    pa.Wc[m] = (u16*)(w + o_Wcm[m]);
    ra.W1[m] = W1a[m]; ra.b1[m] = b1a[m]; ra.bmod[m] = bmoda[m]; ra.w2[m] = w2a[m];
    ra.qr[m] = (float*)(w + o_qrm[m]);
    ga.A[m] = Amoda[m]; ga.B[m] = (const u16*)(w + o_Wcm[m]); ga.w2[m] = w2a[m];
    ga.qd[m] = (float*)(w + o_qdm[m]); ga.qs[m] = (float*)(w + o_qsm[m]);
    ga.K[m] = Ks[m];
    aa.qd[m] = (const float*)(w + o_qdm[m]);
    aa.qs[m] = (const float*)(w + o_qsm[m]);
    aa.qr[m] = (const float*)(w + o_qrm[m]);
  }
  aa.PdAll = (const u16*)(w + o_PdAll);
  aa.PsAll = (const u16*)(w + o_PsAll);
  aa.PrAll = (const u16*)(w + o_PrAll);
  aa.eid = eid; aa.offs = offs; aa.src = esrc; aa.etyp = et;
  aa.alphaP = alphaP; aa.gammaP = gammaP;
  aa.outp = outp; aa.N = N; aa.NR = NR; aa.E = E;

  prep_wc_all<<<dim3((KMAX + 255) / 256, 256, 3), 256, 0, stream>>>(pa);
  prep_pr_all<<<dim3(NR, 1, 3), 128, 0, stream>>>(ra);
  gemm_fused<<<dim3(NT16, 3), 256, 0, stream>>>(ga);
  aggregate_all<<<(N + 3) / 4, 256, 0, stream>>>(aa);
}

// Round 14
// 290.004 us; speedup vs baseline: 1.2331x; 1.0267x over previous
//
#include <hip/hip_runtime.h>
#include <hip/hip_bf16.h>

typedef unsigned short u16;
typedef unsigned int u32;
typedef __bf16 bf16x8 __attribute__((ext_vector_type(8)));
typedef float f32x4 __attribute__((ext_vector_type(4)));

#define DIM 128
#define NTMAX 24   // max K/32 (TXT=768)

__device__ __forceinline__ u16 f2bf_rne(float x) {
  u32 u = __float_as_uint(x);
  return (u16)((u + 0x7fffu + ((u >> 16) & 1u)) >> 16);
}
__device__ __forceinline__ float lrelu(float x) { return x > 0.f ? x : 0.01f * x; }
__device__ __forceinline__ int iclamp(int v, int hi) { return v < 0 ? 0 : (v >= hi ? hi - 1 : v); }
__device__ __forceinline__ float sane(float x) { return (x == x) ? x : 0.f; }

__device__ __forceinline__ float wred_max(float v) {
  #pragma unroll
  for (int o = 32; o > 0; o >>= 1) v = fmaxf(v, __shfl_xor(v, o, 64));
  return v;
}
__device__ __forceinline__ float wred_sum(float v) {
  #pragma unroll
  for (int o = 32; o > 0; o >>= 1) v += __shfl_xor(v, o, 64);
  return v;
}

// ---------------- CSR build ----------------
__global__ void hist_k(const int* __restrict__ dst, int* __restrict__ cnt, int E, int N) {
  int e = blockIdx.x * blockDim.x + threadIdx.x;
  if (e < E) {
    int d = dst[e];
    if (d >= 0 && d < N) atomicAdd(&cnt[d], 1);
  }
}

__global__ __launch_bounds__(1024) void scan_k(const int* __restrict__ cnt,
                                               int* __restrict__ offs, int N) {
  __shared__ int sums[1024];
  int t = threadIdx.x;
  int chunk = (N + 1023) >> 10;
  int base = t * chunk;
  int s = 0;
  for (int i = 0; i < chunk; ++i) { int idx = base + i; if (idx < N) s += cnt[idx]; }
  sums[t] = s;
  __syncthreads();
  for (int off = 1; off < 1024; off <<= 1) {
    int v = (t >= off) ? sums[t - off] : 0;
    __syncthreads();
    sums[t] += v;
    __syncthreads();
  }
  int prefix = (t > 0) ? sums[t - 1] : 0;
  for (int i = 0; i < chunk; ++i) {
    int idx = base + i;
    if (idx < N) { offs[idx] = prefix; prefix += cnt[idx]; }
  }
  if (t == 1023) offs[N] = sums[1023];
}

// scatter packed (etyp<<16)|src in CSR order — clamped at pack time
__global__ void scatter_k(const int* __restrict__ dst, const int* __restrict__ src,
                          const int* __restrict__ etyp,
                          const int* __restrict__ offs,
                          int* __restrict__ cursor, u32* __restrict__ sortedST,
                          int E, int N, int NR) {
  int e = blockIdx.x * blockDim.x + threadIdx.x;
  if (e < E) {
    int d = dst[e];
    if (d >= 0 && d < N) {
      int pos = offs[d] + atomicAdd(&cursor[d], 1);
      if (pos >= 0 && pos < E) {
        u32 s = (u32)iclamp(src[e], N);
        u32 t = (u32)iclamp(etyp[e], NR);
        sortedST[pos] = (t << 16) | s;
      }
    }
  }
}

// ================= structs =================
struct PrepArgs {
  const float* W1[3]; const float* Wmod[3]; int K[3]; int isCopy[3];
  u16* Wc[3];
};
struct PrArgs {
  const float* rel; const float* W1[3]; const float* b1[3];
  const float* bmod[3]; const float* w2[3];
  u16* PrAll; float* qr[3]; int NR;
};
struct GArgs {
  const float* A[3]; const u16* B[3]; const float* w2[3];
  u16* PdAll; u16* PsAll; float* qd[3]; float* qs[3];
  int M; int K[3];
};
struct AgArgs {
  const u32* sortedST; const int* offs;
  const float* qd[3]; const float* qs[3]; const float* qr[3];
  const u16* PdAll; const u16* PsAll; const u16* PrAll;
  const float* alphaP; const float* gammaP;
  float* outp; int N; int NR; int E;
};

// combined bf16 B, PACKED trip-major: Wc[((k>>5)*256 + o)*32 + (k&31)]
__global__ void prep_wc_all(PrepArgs a) {
  int m = blockIdx.z;
  int K = a.K[m];
  int k = blockIdx.x * blockDim.x + threadIdx.x;
  int o = blockIdx.y;                       // 0..255
  if (k >= K) return;
  int half = (o >= 128) ? 128 : 0;
  int oo = o & 127;
  const float* W1 = a.W1[m];
  float acc;
  if (a.isCopy[m]) {
    acc = W1[oo * 384 + half + k];
  } else {
    const float* Wm = a.Wmod[m];
    acc = 0.f;
    for (int i = 0; i < 128; ++i)
      acc += W1[oo * 384 + half + i] * Wm[i * K + k];
  }
  a.Wc[m][((size_t)(k >> 5) * 256 + o) * 32 + (k & 31)] = f2bf_rne(acc);
}

// PrAll[r][m*128+o] (bf16, interleaved) + qr[m][r] (f32); grid (NR,1,3)
__global__ __launch_bounds__(128) void prep_pr_all(PrArgs a) {
  __shared__ float red[128];
  int m = blockIdx.z;
  int r = blockIdx.x;
  if (r >= a.NR) return;
  int o = threadIdx.x;
  const float* W1 = a.W1[m];
  float acc = a.b1[m][o];
  for (int i = 0; i < 128; ++i)
    acc += W1[o * 384 + 256 + i] * a.rel[r * 128 + i];
  const float* bmod = a.bmod[m];
  if (bmod != nullptr) {
    for (int i = 0; i < 128; ++i)
      acc += (W1[o * 384 + i] + W1[o * 384 + 128 + i]) * bmod[i];
  }
  a.PrAll[(size_t)r * 384 + m * 128 + o] = f2bf_rne(acc);
  red[o] = acc * a.w2[m][o];
  __syncthreads();
  for (int s = 64; s > 0; s >>= 1) {
    if (o < s) red[o] += red[o + s];
    __syncthreads();
  }
  if (o == 0) a.qr[m][r] = sane(red[0]);
}

// ---------- fused convert+GEMM with software-pipelined B loads ----------
__global__ __launch_bounds__(256) void gemm_fused(GArgs g) {
  __shared__ u16 Als[NTMAX * 16 * 32];   // ≤24 KB
  __shared__ float qpart[4][16];
  int m = blockIdx.y;
  int M = g.M, K = g.K[m];
  int nt = K >> 5;                        // 4 / 16 / 24 (even)
  const u16* Bpk = g.B[m];
  const float* w2 = g.w2[m];
  int tid = threadIdx.x;
  int lane = tid & 63, wv = tid >> 6;
  int quad = lane >> 4, l16 = lane & 15;
  int row0 = blockIdx.x * 16;

  {
    int srow = tid >> 4;
    int scol = (tid & 15) * 2;
    int gr = row0 + srow;
    bool v = gr < M;
    const float* Ag = g.A[m] + (size_t)(v ? gr : 0) * K;
    for (int kb = 0; kb < nt; ++kb) {
      float2 x = make_float2(0.f, 0.f);
      if (v) x = *reinterpret_cast<const float2*>(Ag + kb * 32 + scol);
      *reinterpret_cast<u32*>(&Als[(kb * 16 + srow) * 32 + scol]) =
          (u32)f2bf_rne(x.x) | ((u32)f2bf_rne(x.y) << 16);
    }
  }
  __syncthreads();

  const u16* Bpg = Bpk + (size_t)(wv * 64 + l16) * 32 + quad * 8;

  f32x4 acc[4];
  #pragma unroll
  for (int t = 0; t < 4; ++t) acc[t] = (f32x4){0.f, 0.f, 0.f, 0.f};

  // prologue: load kb=0 and kb=1 fragments
  bf16x8 bc[8];
  {
    const u16* p0 = Bpg;
    const u16* p1 = Bpg + ((1 < nt) ? 8192 : 0);
    bc[0] = *reinterpret_cast<const bf16x8*>(p0);
    bc[1] = *reinterpret_cast<const bf16x8*>(p0 + 512);
    bc[2] = *reinterpret_cast<const bf16x8*>(p0 + 1024);
    bc[3] = *reinterpret_cast<const bf16x8*>(p0 + 1536);
    bc[4] = *reinterpret_cast<const bf16x8*>(p1);
    bc[5] = *reinterpret_cast<const bf16x8*>(p1 + 512);
    bc[6] = *reinterpret_cast<const bf16x8*>(p1 + 1024);
    bc[7] = *reinterpret_cast<const bf16x8*>(p1 + 1536);
  }

  for (int kb = 0; kb < nt; kb += 2) {
    // prefetch next pair (clamped on last trip — redundant loads, unused)
    int kn0 = (kb + 2 < nt) ? kb + 2 : kb;
    int kn1 = (kb + 3 < nt) ? kb + 3 : kb;
    const u16* pn0 = Bpg + (size_t)kn0 * 8192;
    const u16* pn1 = Bpg + (size_t)kn1 * 8192;
    bf16x8 bn[8];
    bn[0] = *reinterpret_cast<const bf16x8*>(pn0);
    bn[1] = *reinterpret_cast<const bf16x8*>(pn0 + 512);
    bn[2] = *reinterpret_cast<const bf16x8*>(pn0 + 1024);
    bn[3] = *reinterpret_cast<const bf16x8*>(pn0 + 1536);
    bn[4] = *reinterpret_cast<const bf16x8*>(pn1);
    bn[5] = *reinterpret_cast<const bf16x8*>(pn1 + 512);
    bn[6] = *reinterpret_cast<const bf16x8*>(pn1 + 1024);
    bn[7] = *reinterpret_cast<const bf16x8*>(pn1 + 1536);

    bf16x8 a0 = *reinterpret_cast<const bf16x8*>(&Als[(kb * 16 + l16) * 32 + quad * 8]);
    bf16x8 a1 = *reinterpret_cast<const bf16x8*>(&Als[((kb + 1) * 16 + l16) * 32 + quad * 8]);

    acc[0] = __builtin_amdgcn_mfma_f32_16x16x32_bf16(a0, bc[0], acc[0], 0, 0, 0);
    acc[1] = __builtin_amdgcn_mfma_f32_16x16x32_bf16(a0, bc[1], acc[1], 0, 0, 0);
    acc[2] = __builtin_amdgcn_mfma_f32_16x16x32_bf16(a0, bc[2], acc[2], 0, 0, 0);
    acc[3] = __builtin_amdgcn_mfma_f32_16x16x32_bf16(a0, bc[3], acc[3], 0, 0, 0);
    acc[0] = __builtin_amdgcn_mfma_f32_16x16x32_bf16(a1, bc[4], acc[0], 0, 0, 0);
    acc[1] = __builtin_amdgcn_mfma_f32_16x16x32_bf16(a1, bc[5], acc[1], 0, 0, 0);
    acc[2] = __builtin_amdgcn_mfma_f32_16x16x32_bf16(a1, bc[6], acc[2], 0, 0, 0);
    acc[3] = __builtin_amdgcn_mfma_f32_16x16x32_bf16(a1, bc[7], acc[3], 0, 0, 0);

    #pragma unroll
    for (int u = 0; u < 8; ++u) bc[u] = bn[u];
  }

  u16* PdAll = g.PdAll;
  u16* PsAll = g.PsAll;
  float w2c[4];
  #pragma unroll
  for (int t = 0; t < 4; ++t) w2c[t] = w2[(wv & 1) * 64 + t * 16 + l16];

  float part[4];
  #pragma unroll
  for (int r = 0; r < 4; ++r) {
    int rr = row0 + quad * 4 + r;
    bool ok = rr < M;
    float qp = 0.f;
    #pragma unroll
    for (int t = 0; t < 4; ++t) {
      int c = (wv & 1) * 64 + t * 16 + l16;
      if (ok) {
        if (wv < 2) PdAll[(size_t)rr * 384 + m * 128 + c] = f2bf_rne(acc[t][r]);
        else        PsAll[(size_t)rr * 384 + m * 128 + c] = f2bf_rne(acc[t][r]);
      }
      qp += acc[t][r] * w2c[t];
    }
    #pragma unroll
    for (int mk = 1; mk < 16; mk <<= 1) qp += __shfl_xor(qp, mk, 64);
    part[r] = qp;
  }
  if (l16 == 0) {
    #pragma unroll
    for (int r = 0; r < 4; ++r) qpart[wv][quad * 4 + r] = part[r];
  }
  __syncthreads();
  if (tid < 32) {
    int row = tid & 15;
    int rr = row0 + row;
    if (rr < M) {
      if (tid < 16) g.qd[m][rr] = sane(qpart[0][row] + qpart[1][row]);
      else          g.qs[m][rr] = sane(qpart[2][row] + qpart[3][row]);
    }
  }
}

// fused 3-modality ONLINE-softmax aggregate; packed (typ<<16|src); ×4 j-unroll
__global__ __launch_bounds__(256) void aggregate_all(AgArgs a) {
  int n = blockIdx.x * 4 + (threadIdx.x >> 6);
  if (n >= a.N) return;
  int lane = threadIdx.x & 63;
  int E = a.E;
  int eb = a.offs[n], ee = a.offs[n + 1];
  if (eb < 0) eb = 0;
  if (eb > E) eb = E;
  if (ee < eb) ee = eb;
  if (ee > E) ee = E;
  int En = ee - eb;

  float al = a.alphaP[0];
  if (!(al > 0.f && al < 1.f)) al = 0.1f;
  float ga = a.gammaP[0];
  if (!(ga > 0.f && ga < 1.f)) ga = 0.8f;
  float coef[3] = {1.f - al - ga, al, ga};

  float qdn[3];
  #pragma unroll
  for (int m = 0; m < 3; ++m) qdn[m] = sane(a.qd[m][n]);

  const u16* PsAll = a.PsAll;
  const u16* PrAll = a.PrAll;
  int dlo = 2 * lane;

  // single pass: online softmax + accumulation
  float rm[3] = {-1e30f, -1e30f, -1e30f};   // running max
  float z[3] = {0.f, 0.f, 0.f};
  float a0[3] = {0.f, 0.f, 0.f};
  float a1[3] = {0.f, 0.f, 0.f};
  for (int c0 = 0; c0 < En; c0 += 64) {
    int cn = min(64, En - c0);
    u32 stp = 0;
    float bm[3] = {-1e30f, -1e30f, -1e30f};
    if (lane < cn) {
      stp = a.sortedST[eb + c0 + lane];
      int s = (int)(stp & 0xffffu);
      int t = (int)(stp >> 16);
      #pragma unroll
      for (int m = 0; m < 3; ++m)
        bm[m] = lrelu(qdn[m] + a.qs[m][s] + a.qr[m][t]);
    }
    float wr[3];
    #pragma unroll
    for (int m = 0; m < 3; ++m) {
      float cm = wred_max(bm[m]);
      float nm = fmaxf(rm[m], cm);
      float sc = __expf(fmaxf(rm[m] - nm, -80.f));
      z[m] *= sc; a0[m] *= sc; a1[m] *= sc;
      rm[m] = nm;
      wr[m] = (lane < cn) ? __expf(fmaxf(bm[m] - nm, -80.f)) : 0.f;
      z[m] += wr[m];
    }

    int cnR = (cn + 3) & ~3;   // tail lanes: wr=0, stp=0 → harmless
    for (int j = 0; j < cnR; j += 4) {
      u32 stj[4];
      float wj[4][3];
      #pragma unroll
      for (int u = 0; u < 4; ++u) {
        stj[u] = __shfl(stp, j + u, 64);
        wj[u][0] = __shfl(wr[0], j + u, 64);
        wj[u][1] = __shfl(wr[1], j + u, 64);
        wj[u][2] = __shfl(wr[2], j + u, 64);
      }
      u32 pu[4][3], ru[4][3];
      #pragma unroll
      for (int u = 0; u < 4; ++u) {
        const u16* ps = PsAll + (size_t)(stj[u] & 0xffffu) * 384 + dlo;
        const u16* pr = PrAll + (size_t)(stj[u] >> 16) * 384 + dlo;
        #pragma unroll
        for (int m = 0; m < 3; ++m) {
          pu[u][m] = *reinterpret_cast<const u32*>(ps + m * 128);
          ru[u][m] = *reinterpret_cast<const u32*>(pr + m * 128);
        }
      }
      #pragma unroll
      for (int u = 0; u < 4; ++u) {
        #pragma unroll
        for (int m = 0; m < 3; ++m) {
          float ps0 = __uint_as_float(pu[u][m] << 16);
          float ps1 = __uint_as_float(pu[u][m] & 0xffff0000u);
          float pr0 = __uint_as_float(ru[u][m] << 16);
          float pr1 = __uint_as_float(ru[u][m] & 0xffff0000u);
          a0[m] = fmaf(wj[u][m], ps0 + pr0, a0[m]);
          a1[m] = fmaf(wj[u][m], ps1 + pr1, a1[m]);
        }
      }
    }
  }
  #pragma unroll
  for (int m = 0; m < 3; ++m) z[m] = wred_sum(z[m]);

  float o0 = 0.f, o1 = 0.f;
  const u16* pd = a.PdAll + (size_t)n * 384 + dlo;
  #pragma unroll
  for (int m = 0; m < 3; ++m) {
    float h0 = 0.f, h1 = 0.f;
    if (En > 0 && z[m] > 0.f) {
      float rz = 1.f / z[m];
      u32 du = *reinterpret_cast<const u32*>(pd + m * 128);
      float pd0 = __uint_as_float(du << 16), pd1 = __uint_as_float(du & 0xffff0000u);
      h0 = lrelu(pd0 + a0[m] * rz);
      h1 = lrelu(pd1 + a1[m] * rz);
    }
    o0 = fmaf(coef[m], h0, o0);
    o1 = fmaf(coef[m], h1, o1);
  }
  float* op = a.outp + (size_t)n * 128 + dlo;
  op[0] = sane(o0);
  op[1] = sane(o1);
}

extern "C" void kernel_launch(void* const* d_in, const int* in_sizes, int n_in,
                              void* d_out, int out_size, void* d_ws, size_t ws_size,
                              hipStream_t stream) {
  const int* ei        = (const int*)d_in[1];
  const int* et        = (const int*)d_in[2];
  const float* visual  = (const float*)d_in[3];
  const float* textual = (const float*)d_in[4];
  const float* semb    = (const float*)d_in[5];
  const float* relemb  = (const float*)d_in[6];
  const float* W1s = (const float*)d_in[7];
  const float* b1s = (const float*)d_in[8];
  const float* w2s = (const float*)d_in[9];
  const float* W1v = (const float*)d_in[10];
  const float* b1v = (const float*)d_in[11];
  const float* w2v = (const float*)d_in[12];
  const float* W1t = (const float*)d_in[13];
  const float* b1t = (const float*)d_in[14];
  const float* w2t = (const float*)d_in[15];
  const float* Wv  = (const float*)d_in[16];
  const float* bv  = (const float*)d_in[17];
  const float* Wt  = (const float*)d_in[18];
  const float* bt  = (const float*)d_in[19];
  const float* alphaP = (const float*)d_in[20];
  const float* gammaP = (const float*)d_in[21];
  float* outp = (float*)d_out;

  const int E   = in_sizes[2];
  const int N   = in_sizes[5] / DIM;
  const int NR  = in_sizes[6] / DIM;
  const int VIS = in_sizes[3] / N;   // 512
  const int TXT = in_sizes[4] / N;   // 768
  const int KMAX = (TXT > VIS) ? TXT : VIS;
  int Ks[3] = {DIM, VIS, TXT};
  const int NT16 = (N + 15) / 16;

  const float* W1a[3]   = {W1s, W1v, W1t};
  const float* b1a[3]   = {b1s, b1v, b1t};
  const float* w2a[3]   = {w2s, w2v, w2t};
  const float* Wmoda[3] = {nullptr, Wv, Wt};
  const float* bmoda[3] = {nullptr, bv, bt};
  const float* Amoda[3] = {semb, visual, textual};

  const int* esrc = ei;
  const int* edst = ei + E;
  int egrid = (E + 255) / 256;

  size_t off = 0;
  auto take = [&](size_t bytes) -> size_t {
    size_t o = off;
    off = (off + bytes + 255) & ~(size_t)255;
    return o;
  };
  size_t o_cnt  = take((size_t)2 * N * 4);
  size_t o_offs = take((size_t)(N + 1) * 4);
  size_t o_st   = take((size_t)E * 4);
  size_t meta_end = off;
  size_t o_qdm[3], o_qsm[3], o_qrm[3], o_Wcm[3];
  for (int m = 0; m < 3; ++m) {
    o_qdm[m] = take((size_t)N * 4);
    o_qsm[m] = take((size_t)N * 4);
    o_qrm[m] = take((size_t)NR * 4);
    o_Wcm[m] = take((size_t)256 * Ks[m] * 2);
  }
  size_t o_PrAll = take((size_t)NR * 384 * 2);
  size_t o_PdAll = take((size_t)N * 384 * 2);
  size_t o_PsAll = take((size_t)N * 384 * 2);
  size_t need = off;                           // ~17.5 MB

  if (ws_size < need) {
    hipMemsetAsync(d_out, 0, (size_t)out_size * 4, stream);  // finite diagnostic
    return;
  }

  char* w = (char*)d_ws;
  int* counts = (int*)(w + o_cnt);
  int* cursor = counts + N;
  int* offs   = (int*)(w + o_offs);
  u32* sortedST = (u32*)(w + o_st);

  hipMemsetAsync(w, 0, meta_end, stream);
  hist_k<<<egrid, 256, 0, stream>>>(edst, counts, E, N);
  scan_k<<<1, 1024, 0, stream>>>(counts, offs, N);
  scatter_k<<<egrid, 256, 0, stream>>>(edst, esrc, et, offs, cursor, sortedST, E, N, NR);

  PrepArgs pa;
  PrArgs ra;
  GArgs ga;
  AgArgs aa;
  ra.rel = relemb; ra.NR = NR;
  ra.PrAll = (u16*)(w + o_PrAll);
  ga.M = N;
  ga.PdAll = (u16*)(w + o_PdAll);
  ga.PsAll = (u16*)(w + o_PsAll);
  for (int m = 0; m < 3; ++m) {
    pa.W1[m] = W1a[m]; pa.Wmod[m] = Wmoda[m]; pa.K[m] = Ks[m];
    pa.isCopy[m] = (m == 0);
    pa.Wc[m] = (u16*)(w + o_Wcm[m]);
    ra.W1[m] = W1a[m]; ra.b1[m] = b1a[m]; ra.bmod[m] = bmoda[m]; ra.w2[m] = w2a[m];
    ra.qr[m] = (float*)(w + o_qrm[m]);
    ga.A[m] = Amoda[m]; ga.B[m] = (const u16*)(w + o_Wcm[m]); ga.w2[m] = w2a[m];
    ga.qd[m] = (float*)(w + o_qdm[m]); ga.qs[m] = (float*)(w + o_qsm[m]);
    ga.K[m] = Ks[m];
    aa.qd[m] = (const float*)(w + o_qdm[m]);
    aa.qs[m] = (const float*)(w + o_qsm[m]);
    aa.qr[m] = (const float*)(w + o_qrm[m]);
  }
  aa.PdAll = (const u16*)(w + o_PdAll);
  aa.PsAll = (const u16*)(w + o_PsAll);
  aa.PrAll = (const u16*)(w + o_PrAll);
  aa.sortedST = sortedST; aa.offs = offs;
  aa.alphaP = alphaP; aa.gammaP = gammaP;
  aa.outp = outp; aa.N = N; aa.NR = NR; aa.E = E;

  prep_wc_all<<<dim3((KMAX + 255) / 256, 256, 3), 256, 0, stream>>>(pa);
  prep_pr_all<<<dim3(NR, 1, 3), 128, 0, stream>>>(ra);
  gemm_fused<<<dim3(NT16, 3), 256, 0, stream>>>(ga);
  aggregate_all<<<(N + 3) / 4, 256, 0, stream>>>(aa);
}

// Round 15
// 277.224 us; speedup vs baseline: 1.2900x; 1.0461x over previous
//
#include <hip/hip_runtime.h>
#include <hip/hip_bf16.h>

typedef unsigned short u16;
typedef unsigned int u32;
typedef __bf16 bf16x8 __attribute__((ext_vector_type(8)));
typedef float f32x4 __attribute__((ext_vector_type(4)));

#define DIM 128

__device__ __forceinline__ u16 f2bf_rne(float x) {
  u32 u = __float_as_uint(x);
  return (u16)((u + 0x7fffu + ((u >> 16) & 1u)) >> 16);
}
__device__ __forceinline__ u32 packbf2(float x, float y) {
  return (u32)f2bf_rne(x) | ((u32)f2bf_rne(y) << 16);
}
__device__ __forceinline__ float lrelu(float x) { return x > 0.f ? x : 0.01f * x; }
__device__ __forceinline__ int iclamp(int v, int hi) { return v < 0 ? 0 : (v >= hi ? hi - 1 : v); }
__device__ __forceinline__ float sane(float x) { return (x == x) ? x : 0.f; }

__device__ __forceinline__ float wred_max(float v) {
  #pragma unroll
  for (int o = 32; o > 0; o >>= 1) v = fmaxf(v, __shfl_xor(v, o, 64));
  return v;
}
__device__ __forceinline__ float wred_sum(float v) {
  #pragma unroll
  for (int o = 32; o > 0; o >>= 1) v += __shfl_xor(v, o, 64);
  return v;
}

// ---------------- CSR build ----------------
__global__ void hist_k(const int* __restrict__ dst, int* __restrict__ cnt, int E, int N) {
  int e = blockIdx.x * blockDim.x + threadIdx.x;
  if (e < E) {
    int d = dst[e];
    if (d >= 0 && d < N) atomicAdd(&cnt[d], 1);
  }
}

__global__ __launch_bounds__(1024) void scan_k(const int* __restrict__ cnt,
                                               int* __restrict__ offs, int N) {
  __shared__ int sums[1024];
  int t = threadIdx.x;
  int chunk = (N + 1023) >> 10;
  int base = t * chunk;
  int s = 0;
  for (int i = 0; i < chunk; ++i) { int idx = base + i; if (idx < N) s += cnt[idx]; }
  sums[t] = s;
  __syncthreads();
  for (int off = 1; off < 1024; off <<= 1) {
    int v = (t >= off) ? sums[t - off] : 0;
    __syncthreads();
    sums[t] += v;
    __syncthreads();
  }
  int prefix = (t > 0) ? sums[t - 1] : 0;
  for (int i = 0; i < chunk; ++i) {
    int idx = base + i;
    if (idx < N) { offs[idx] = prefix; prefix += cnt[idx]; }
  }
  if (t == 1023) offs[N] = sums[1023];
}

// scatter packed (etyp<<16)|src in CSR order — clamped at pack time
__global__ void scatter_k(const int* __restrict__ dst, const int* __restrict__ src,
                          const int* __restrict__ etyp,
                          const int* __restrict__ offs,
                          int* __restrict__ cursor, u32* __restrict__ sortedST,
                          int E, int N, int NR) {
  int e = blockIdx.x * blockDim.x + threadIdx.x;
  if (e < E) {
    int d = dst[e];
    if (d >= 0 && d < N) {
      int pos = offs[d] + atomicAdd(&cursor[d], 1);
      if (pos >= 0 && pos < E) {
        u32 s = (u32)iclamp(src[e], N);
        u32 t = (u32)iclamp(etyp[e], NR);
        sortedST[pos] = (t << 16) | s;
      }
    }
  }
}

// ================= structs =================
struct PrepArgs {
  const float* W1[3]; const float* Wmod[3]; int K[3]; int isCopy[3];
  u16* Wc[3];
};
struct PrArgs {
  const float* rel; const float* W1[3]; const float* b1[3];
  const float* bmod[3]; const float* w2[3];
  u16* PrAll; float* qr[3]; int NR;
};
struct GArgs {
  const float* A[3]; const u16* B[3]; const float* w2[3];
  u16* PdAll; u16* PsAll; float* qd[3]; float* qs[3];
  int M; int K[3];
};
struct AgArgs {
  const u32* sortedST; const int* offs;
  const float* qd[3]; const float* qs[3]; const float* qr[3];
  const u16* PdAll; const u16* PsAll; const u16* PrAll;
  const float* alphaP; const float* gammaP;
  float* outp; int N; int NR; int E;
};

// combined bf16 B, PACKED trip-major: Wc[((k>>5)*256 + o)*32 + (k&31)]
__global__ void prep_wc_all(PrepArgs a) {
  int m = blockIdx.z;
  int K = a.K[m];
  int k = blockIdx.x * blockDim.x + threadIdx.x;
  int o = blockIdx.y;                       // 0..255
  if (k >= K) return;
  int half = (o >= 128) ? 128 : 0;
  int oo = o & 127;
  const float* W1 = a.W1[m];
  float acc;
  if (a.isCopy[m]) {
    acc = W1[oo * 384 + half + k];
  } else {
    const float* Wm = a.Wmod[m];
    acc = 0.f;
    for (int i = 0; i < 128; ++i)
      acc += W1[oo * 384 + half + i] * Wm[i * K + k];
  }
  a.Wc[m][((size_t)(k >> 5) * 256 + o) * 32 + (k & 31)] = f2bf_rne(acc);
}

// PrAll[r][m*128+o] (bf16, interleaved) + qr[m][r] (f32); grid (NR,1,3)
__global__ __launch_bounds__(128) void prep_pr_all(PrArgs a) {
  __shared__ float red[128];
  int m = blockIdx.z;
  int r = blockIdx.x;
  if (r >= a.NR) return;
  int o = threadIdx.x;
  const float* W1 = a.W1[m];
  float acc = a.b1[m][o];
  for (int i = 0; i < 128; ++i)
    acc += W1[o * 384 + 256 + i] * a.rel[r * 128 + i];
  const float* bmod = a.bmod[m];
  if (bmod != nullptr) {
    for (int i = 0; i < 128; ++i)
      acc += (W1[o * 384 + i] + W1[o * 384 + 128 + i]) * bmod[i];
  }
  a.PrAll[(size_t)r * 384 + m * 128 + o] = f2bf_rne(acc);
  red[o] = acc * a.w2[m][o];
  __syncthreads();
  for (int s = 64; s > 0; s >>= 1) {
    if (o < s) red[o] += red[o + s];
    __syncthreads();
  }
  if (o == 0) a.qr[m][r] = sane(red[0]);
}

// ---------- 64-row-tile convert+GEMM: B read once per 64 A-rows (4× less L2) ----
// grid (M/64, 3), 256 thr; wave wv: cols wv*64..+64 over ALL 64 rows.
// A staged in 32-KB LDS chunks (8 kb-steps); ≤3 chunks (2 barriers each).
// C/D layout (verified): col = lane&15, row = (lane>>4)*4 + reg
__global__ __launch_bounds__(256) void gemm_fused(GArgs g) {
  __shared__ u16 Als[8 * 64 * 32];     // 32 KB chunk
  __shared__ float qpart[4][64];
  int m = blockIdx.y;
  int M = g.M, K = g.K[m];
  int nt = K >> 5;                      // 4 / 16 / 24
  const u16* Bpk = g.B[m];
  const float* w2 = g.w2[m];
  int tid = threadIdx.x;
  int lane = tid & 63, wv = tid >> 6;
  int quad = lane >> 4, l16 = lane & 15;
  int row0 = blockIdx.x * 64;

  // staging map: thread → row tid>>2 (0..63), k-segment (tid&3)*64
  int srow = tid >> 2;
  int kseg = (tid & 3) * 64;
  int grow = row0 + srow;
  if (grow >= M) grow = M - 1;          // dup loads; stores guarded
  const float* Ag = g.A[m] + (size_t)grow * K;

  const u16* Bpg = Bpk + (size_t)(wv * 64 + l16) * 32 + quad * 8;

  f32x4 acc[4][4];
  #pragma unroll
  for (int rg = 0; rg < 4; ++rg)
    #pragma unroll
    for (int t = 0; t < 4; ++t) acc[rg][t] = (f32x4){0.f, 0.f, 0.f, 0.f};

  int nchunk = (nt + 7) >> 3;
  for (int c = 0; c < nchunk; ++c) {
    int kbase = c << 8;                 // c*256
    __syncthreads();
    #pragma unroll
    for (int i = 0; i < 16; ++i) {
      int kl = kseg + i * 4;
      int kg = kbase + kl;
      if (kg < K) {
        float4 v = *reinterpret_cast<const float4*>(Ag + kg);
        u32* d = reinterpret_cast<u32*>(&Als[((kl >> 5) * 64 + srow) * 32 + (kl & 31)]);
        d[0] = packbf2(v.x, v.y);
        d[1] = packbf2(v.z, v.w);
      }
    }
    __syncthreads();
    int kbR = nt - (c << 3);
    if (kbR > 8) kbR = 8;
    for (int kbl = 0; kbl < kbR; ++kbl) {
      const u16* bp = Bpg + (size_t)((c << 3) + kbl) * 8192;
      bf16x8 b0 = *reinterpret_cast<const bf16x8*>(bp);
      bf16x8 b1 = *reinterpret_cast<const bf16x8*>(bp + 512);
      bf16x8 b2 = *reinterpret_cast<const bf16x8*>(bp + 1024);
      bf16x8 b3 = *reinterpret_cast<const bf16x8*>(bp + 1536);
      #pragma unroll
      for (int rg = 0; rg < 4; ++rg) {
        bf16x8 a = *reinterpret_cast<const bf16x8*>(
            &Als[(kbl * 64 + rg * 16 + l16) * 32 + quad * 8]);
        acc[rg][0] = __builtin_amdgcn_mfma_f32_16x16x32_bf16(a, b0, acc[rg][0], 0, 0, 0);
        acc[rg][1] = __builtin_amdgcn_mfma_f32_16x16x32_bf16(a, b1, acc[rg][1], 0, 0, 0);
        acc[rg][2] = __builtin_amdgcn_mfma_f32_16x16x32_bf16(a, b2, acc[rg][2], 0, 0, 0);
        acc[rg][3] = __builtin_amdgcn_mfma_f32_16x16x32_bf16(a, b3, acc[rg][3], 0, 0, 0);
      }
    }
  }

  // epilogue: interleaved table stores + fused q (per row-group, then cross-wave)
  u16* PdAll = g.PdAll;
  u16* PsAll = g.PsAll;
  float w2c[4];
  #pragma unroll
  for (int t = 0; t < 4; ++t) w2c[t] = w2[(wv & 1) * 64 + t * 16 + l16];

  #pragma unroll
  for (int rg = 0; rg < 4; ++rg) {
    float part[4];
    #pragma unroll
    for (int r = 0; r < 4; ++r) {
      int rr = row0 + rg * 16 + quad * 4 + r;
      bool ok = rr < M;
      float qp = 0.f;
      #pragma unroll
      for (int t = 0; t < 4; ++t) {
        int cc = (wv & 1) * 64 + t * 16 + l16;
        if (ok) {
          if (wv < 2) PdAll[(size_t)rr * 384 + m * 128 + cc] = f2bf_rne(acc[rg][t][r]);
          else        PsAll[(size_t)rr * 384 + m * 128 + cc] = f2bf_rne(acc[rg][t][r]);
        }
        qp += acc[rg][t][r] * w2c[t];
      }
      #pragma unroll
      for (int mk = 1; mk < 16; mk <<= 1) qp += __shfl_xor(qp, mk, 64);
      part[r] = qp;
    }
    if (l16 == 0) {
      #pragma unroll
      for (int r = 0; r < 4; ++r) qpart[wv][rg * 16 + quad * 4 + r] = part[r];
    }
  }
  __syncthreads();
  if (tid < 128) {
    int row = tid & 63;
    int half = tid >> 6;
    int rr = row0 + row;
    if (rr < M) {
      if (half == 0) g.qd[m][rr] = sane(qpart[0][row] + qpart[1][row]);
      else           g.qs[m][rr] = sane(qpart[2][row] + qpart[3][row]);
    }
  }
}

// fused 3-modality ONLINE-softmax aggregate; packed (typ<<16|src); ×4 j-unroll
__global__ __launch_bounds__(256) void aggregate_all(AgArgs a) {
  int n = blockIdx.x * 4 + (threadIdx.x >> 6);
  if (n >= a.N) return;
  int lane = threadIdx.x & 63;
  int E = a.E;
  int eb = a.offs[n], ee = a.offs[n + 1];
  if (eb < 0) eb = 0;
  if (eb > E) eb = E;
  if (ee < eb) ee = eb;
  if (ee > E) ee = E;
  int En = ee - eb;

  float al = a.alphaP[0];
  if (!(al > 0.f && al < 1.f)) al = 0.1f;
  float ga = a.gammaP[0];
  if (!(ga > 0.f && ga < 1.f)) ga = 0.8f;
  float coef[3] = {1.f - al - ga, al, ga};

  float qdn[3];
  #pragma unroll
  for (int m = 0; m < 3; ++m) qdn[m] = sane(a.qd[m][n]);

  const u16* PsAll = a.PsAll;
  const u16* PrAll = a.PrAll;
  int dlo = 2 * lane;

  float rm[3] = {-1e30f, -1e30f, -1e30f};
  float z[3] = {0.f, 0.f, 0.f};
  float a0[3] = {0.f, 0.f, 0.f};
  float a1[3] = {0.f, 0.f, 0.f};
  for (int c0 = 0; c0 < En; c0 += 64) {
    int cn = min(64, En - c0);
    u32 stp = 0;
    float bm[3] = {-1e30f, -1e30f, -1e30f};
    if (lane < cn) {
      stp = a.sortedST[eb + c0 + lane];
      int s = (int)(stp & 0xffffu);
      int t = (int)(stp >> 16);
      #pragma unroll
      for (int m = 0; m < 3; ++m)
        bm[m] = lrelu(qdn[m] + a.qs[m][s] + a.qr[m][t]);
    }
    float wr[3];
    #pragma unroll
    for (int m = 0; m < 3; ++m) {
      float cm = wred_max(bm[m]);
      float nm = fmaxf(rm[m], cm);
      float sc = __expf(fmaxf(rm[m] - nm, -80.f));
      z[m] *= sc; a0[m] *= sc; a1[m] *= sc;
      rm[m] = nm;
      wr[m] = (lane < cn) ? __expf(fmaxf(bm[m] - nm, -80.f)) : 0.f;
      z[m] += wr[m];
    }

    int cnR = (cn + 3) & ~3;
    for (int j = 0; j < cnR; j += 4) {
      u32 stj[4];
      float wj[4][3];
      #pragma unroll
      for (int u = 0; u < 4; ++u) {
        stj[u] = __shfl(stp, j + u, 64);
        wj[u][0] = __shfl(wr[0], j + u, 64);
        wj[u][1] = __shfl(wr[1], j + u, 64);
        wj[u][2] = __shfl(wr[2], j + u, 64);
      }
      u32 pu[4][3], ru[4][3];
      #pragma unroll
      for (int u = 0; u < 4; ++u) {
        const u16* ps = PsAll + (size_t)(stj[u] & 0xffffu) * 384 + dlo;
        const u16* pr = PrAll + (size_t)(stj[u] >> 16) * 384 + dlo;
        #pragma unroll
        for (int m = 0; m < 3; ++m) {
          pu[u][m] = *reinterpret_cast<const u32*>(ps + m * 128);
          ru[u][m] = *reinterpret_cast<const u32*>(pr + m * 128);
        }
      }
      #pragma unroll
      for (int u = 0; u < 4; ++u) {
        #pragma unroll
        for (int m = 0; m < 3; ++m) {
          float ps0 = __uint_as_float(pu[u][m] << 16);
          float ps1 = __uint_as_float(pu[u][m] & 0xffff0000u);
          float pr0 = __uint_as_float(ru[u][m] << 16);
          float pr1 = __uint_as_float(ru[u][m] & 0xffff0000u);
          a0[m] = fmaf(wj[u][m], ps0 + pr0, a0[m]);
          a1[m] = fmaf(wj[u][m], ps1 + pr1, a1[m]);
        }
      }
    }
  }
  #pragma unroll
  for (int m = 0; m < 3; ++m) z[m] = wred_sum(z[m]);

  float o0 = 0.f, o1 = 0.f;
  const u16* pd = a.PdAll + (size_t)n * 384 + dlo;
  #pragma unroll
  for (int m = 0; m < 3; ++m) {
    float h0 = 0.f, h1 = 0.f;
    if (En > 0 && z[m] > 0.f) {
      float rz = 1.f / z[m];
      u32 du = *reinterpret_cast<const u32*>(pd + m * 128);
      float pd0 = __uint_as_float(du << 16), pd1 = __uint_as_float(du & 0xffff0000u);
      h0 = lrelu(pd0 + a0[m] * rz);
      h1 = lrelu(pd1 + a1[m] * rz);
    }
    o0 = fmaf(coef[m], h0, o0);
    o1 = fmaf(coef[m], h1, o1);
  }
  float* op = a.outp + (size_t)n * 128 + dlo;
  op[0] = sane(o0);
  op[1] = sane(o1);
}

extern "C" void kernel_launch(void* const* d_in, const int* in_sizes, int n_in,
                              void* d_out, int out_size, void* d_ws, size_t ws_size,
                              hipStream_t stream) {
  const int* ei        = (const int*)d_in[1];
  const int* et        = (const int*)d_in[2];
  const float* visual  = (const float*)d_in[3];
  const float* textual = (const float*)d_in[4];
  const float* semb    = (const float*)d_in[5];
  const float* relemb  = (const float*)d_in[6];
  const float* W1s = (const float*)d_in[7];
  const float* b1s = (const float*)d_in[8];
  const float* w2s = (const float*)d_in[9];
  const float* W1v = (const float*)d_in[10];
  const float* b1v = (const float*)d_in[11];
  const float* w2v = (const float*)d_in[12];
  const float* W1t = (const float*)d_in[13];
  const float* b1t = (const float*)d_in[14];
  const float* w2t = (const float*)d_in[15];
  const float* Wv  = (const float*)d_in[16];
  const float* bv  = (const float*)d_in[17];
  const float* Wt  = (const float*)d_in[18];
  const float* bt  = (const float*)d_in[19];
  const float* alphaP = (const float*)d_in[20];
  const float* gammaP = (const float*)d_in[21];
  float* outp = (float*)d_out;

  const int E   = in_sizes[2];
  const int N   = in_sizes[5] / DIM;
  const int NR  = in_sizes[6] / DIM;
  const int VIS = in_sizes[3] / N;   // 512
  const int TXT = in_sizes[4] / N;   // 768
  const int KMAX = (TXT > VIS) ? TXT : VIS;
  int Ks[3] = {DIM, VIS, TXT};
  const int NT64 = (N + 63) / 64;

  const float* W1a[3]   = {W1s, W1v, W1t};
  const float* b1a[3]   = {b1s, b1v, b1t};
  const float* w2a[3]   = {w2s, w2v, w2t};
  const float* Wmoda[3] = {nullptr, Wv, Wt};
  const float* bmoda[3] = {nullptr, bv, bt};
  const float* Amoda[3] = {semb, visual, textual};

  const int* esrc = ei;
  const int* edst = ei + E;
  int egrid = (E + 255) / 256;

  size_t off = 0;
  auto take = [&](size_t bytes) -> size_t {
    size_t o = off;
    off = (off + bytes + 255) & ~(size_t)255;
    return o;
  };
  size_t o_cnt  = take((size_t)2 * N * 4);
  size_t o_offs = take((size_t)(N + 1) * 4);
  size_t o_st   = take((size_t)E * 4);
  size_t meta_end = off;
  size_t o_qdm[3], o_qsm[3], o_qrm[3], o_Wcm[3];
  for (int m = 0; m < 3; ++m) {
    o_qdm[m] = take((size_t)N * 4);
    o_qsm[m] = take((size_t)N * 4);
    o_qrm[m] = take((size_t)NR * 4);
    o_Wcm[m] = take((size_t)256 * Ks[m] * 2);
  }
  size_t o_PrAll = take((size_t)NR * 384 * 2);
  size_t o_PdAll = take((size_t)N * 384 * 2);
  size_t o_PsAll = take((size_t)N * 384 * 2);
  size_t need = off;                           // ~17.5 MB

  if (ws_size < need) {
    hipMemsetAsync(d_out, 0, (size_t)out_size * 4, stream);  // finite diagnostic
    return;
  }

  char* w = (char*)d_ws;
  int* counts = (int*)(w + o_cnt);
  int* cursor = counts + N;
  int* offs   = (int*)(w + o_offs);
  u32* sortedST = (u32*)(w + o_st);

  hipMemsetAsync(w, 0, meta_end, stream);
  hist_k<<<egrid, 256, 0, stream>>>(edst, counts, E, N);
  scan_k<<<1, 1024, 0, stream>>>(counts, offs, N);
  scatter_k<<<egrid, 256, 0, stream>>>(edst, esrc, et, offs, cursor, sortedST, E, N, NR);

  PrepArgs pa;
  PrArgs ra;
  GArgs ga;
  AgArgs aa;
  ra.rel = relemb; ra.NR = NR;
  ra.PrAll = (u16*)(w + o_PrAll);
  ga.M = N;
  ga.PdAll = (u16*)(w + o_PdAll);
  ga.PsAll = (u16*)(w + o_PsAll);
  for (int m = 0; m < 3; ++m) {
    pa.W1[m] = W1a[m]; pa.Wmod[m] = Wmoda[m]; pa.K[m] = Ks[m];
    pa.isCopy[m] = (m == 0);
    pa.Wc[m] = (u16*)(w + o_Wcm[m]);
    ra.W1[m] = W1a[m]; ra.b1[m] = b1a[m]; ra.bmod[m] = bmoda[m]; ra.w2[m] = w2a[m];
    ra.qr[m] = (float*)(w + o_qrm[m]);
    ga.A[m] = Amoda[m]; ga.B[m] = (const u16*)(w + o_Wcm[m]); ga.w2[m] = w2a[m];
    ga.qd[m] = (float*)(w + o_qdm[m]); ga.qs[m] = (float*)(w + o_qsm[m]);
    ga.K[m] = Ks[m];
    aa.qd[m] = (const float*)(w + o_qdm[m]);
    aa.qs[m] = (const float*)(w + o_qsm[m]);
    aa.qr[m] = (const float*)(w + o_qrm[m]);
  }
  aa.PdAll = (const u16*)(w + o_PdAll);
  aa.PsAll = (const u16*)(w + o_PsAll);
  aa.PrAll = (const u16*)(w + o_PrAll);
  aa.sortedST = sortedST; aa.offs = offs;
  aa.alphaP = alphaP; aa.gammaP = gammaP;
  aa.outp = outp; aa.N = N; aa.NR = NR; aa.E = E;

  prep_wc_all<<<dim3((KMAX + 255) / 256, 256, 3), 256, 0, stream>>>(pa);
  prep_pr_all<<<dim3(NR, 1, 3), 128, 0, stream>>>(ra);
  gemm_fused<<<dim3(NT64, 3), 256, 0, stream>>>(ga);
  aggregate_all<<<(N + 3) / 4, 256, 0, stream>>>(aa);
}